// Round 4
// baseline (3846.632 us; speedup 1.0000x reference)
//
#include <hip/hip_runtime.h>
#include <hip/hip_bf16.h>
#include <stdint.h>

#define HID 1024
#define VOC 1024
#define BB  32
#define TT  512
#define G4  4096   // 4*HID
#define NBLK 64

typedef float f32x4 __attribute__((ext_vector_type(4)));
typedef short bf16x8 __attribute__((ext_vector_type(8)));
typedef unsigned short u16x8 __attribute__((ext_vector_type(8)));

static __device__ __forceinline__ unsigned short f2bf(float f) {
    union { float f; unsigned u; } v; v.f = f;
    unsigned r = (v.u + 0x7FFFu + ((v.u >> 16) & 1u)) >> 16;  // RTNE
    return (unsigned short)r;
}
static __device__ __forceinline__ float bf2f(unsigned short s) {
    union { unsigned u; float f; } v; v.u = ((unsigned)s) << 16;
    return v.f;
}

// ---------------- f32 -> bf16 conversion, 4 elems/thread ----------------
__global__ void cvt_f32_bf16(const float* __restrict__ in,
                             unsigned short* __restrict__ out, int n4) {
    int i = blockIdx.x * blockDim.x + threadIdx.x;
    if (i >= n4) return;
    float4 v = ((const float4*)in)[i];
    ushort4 o;
    o.x = f2bf(v.x); o.y = f2bf(v.y); o.z = f2bf(v.z); o.w = f2bf(v.w);
    ((ushort4*)out)[i] = o;
}

// ---------------- Phase 1: x_proj GEMM ----------------
// XP[t][b][n] = sum_k x[b][t][k]*W_ih[n][k] + b_ih[n] + b_hh[n], bf16,
// relaid out to [T][B][4H] so the scan reads contiguous per-step chunks.
__global__ __launch_bounds__(256) void gemm_xproj(
    const unsigned short* __restrict__ A, const unsigned short* __restrict__ W,
    const float* __restrict__ bih, const float* __restrict__ bhh,
    unsigned short* __restrict__ XP)
{
    __shared__ unsigned short As[128 * 64];
    __shared__ unsigned short Bs[128 * 64];
    const int tid  = threadIdx.x;
    const int lane = tid & 63;
    const int wid  = tid >> 6;
    const int mt = blockIdx.x & 127;   // 128 M-tiles
    const int nt = blockIdx.x >> 7;    // 32  N-tiles
    const long m0 = (long)mt * 128;
    const long n0 = (long)nt * 128;

    const int wr = wid >> 1, wc = wid & 1;
    const int rl = lane & 15;
    const int kl = (lane >> 4) * 8;

    f32x4 acc[4][4] = {};

    for (int kt = 0; kt < 16; ++kt) {
#pragma unroll
        for (int it = 0; it < 4; ++it) {
            int slot = it * 256 + tid;
            int r = slot >> 3, c8 = slot & 7;
            const unsigned short* ga = A + (m0 + r) * 1024 + kt * 64 + c8 * 8;
            const unsigned short* gb = W + (n0 + r) * 1024 + kt * 64 + c8 * 8;
            char* la = (char*)As + (it * 256 + wid * 64) * 16;
            char* lb = (char*)Bs + (it * 256 + wid * 64) * 16;
            __builtin_amdgcn_global_load_lds(
                (const __attribute__((address_space(1))) void*)ga,
                (__attribute__((address_space(3))) void*)la, 16, 0, 0);
            __builtin_amdgcn_global_load_lds(
                (const __attribute__((address_space(1))) void*)gb,
                (__attribute__((address_space(3))) void*)lb, 16, 0, 0);
        }
        __syncthreads();
#pragma unroll
        for (int kk = 0; kk < 2; ++kk) {
            bf16x8 af[4], bfr[4];
#pragma unroll
            for (int i = 0; i < 4; ++i) {
                int ar = wr * 64 + i * 16 + rl;
                int br = wc * 64 + i * 16 + rl;
                af[i]  = *(const bf16x8*)(As + ar * 64 + kk * 32 + kl);
                bfr[i] = *(const bf16x8*)(Bs + br * 64 + kk * 32 + kl);
            }
#pragma unroll
            for (int i = 0; i < 4; ++i)
#pragma unroll
                for (int j = 0; j < 4; ++j)
                    acc[i][j] = __builtin_amdgcn_mfma_f32_16x16x32_bf16(
                        af[i], bfr[j], acc[i][j], 0, 0, 0);
        }
        __syncthreads();
    }
    // epilogue: m-row = b*512+t  ->  XP row = t*32+b  (relayout)
#pragma unroll
    for (int i = 0; i < 4; ++i)
#pragma unroll
        for (int j = 0; j < 4; ++j)
#pragma unroll
            for (int r = 0; r < 4; ++r) {
                long row = m0 + wr * 64 + i * 16 + (lane >> 4) * 4 + r;
                long col = n0 + wc * 64 + j * 16 + (lane & 15);
                long orow = (row & 511) * 32 + (row >> 9);
                float v = acc[i][j][r] + bih[col] + bhh[col];
                XP[orow * 4096 + col] = f2bf(v);
            }
}

// ---------------- Phase 2: persistent fence-free scan ----------------
// 64 blocks x 512 threads (8 waves), 1 block/CU. Block owns hidden slice
// j0=blockIdx.x*16 for all 4 gates. Wave w=(bh,kq). W_hh pinned in ~128
// VGPRs via named locals + asm keep-alive. All cross-block traffic (h,
// flags) uses relaxed AGENT-scope atomics (sc1, point-of-coherence) -> no
// cache-maintenance fences anywhere. Double-buffered h + full 64-flag
// poll bounds skew to 1 step (safe).
__global__ __launch_bounds__(512, 2) void lstm_scan(
    const unsigned short* __restrict__ Whh,   // [4096][1024] bf16
    const unsigned short* __restrict__ XP,    // [512][32][4096] bf16
    unsigned short* __restrict__ h0,          // [32][1024] bf16 (zeroed)
    unsigned short* __restrict__ h1,          // [32][1024] bf16
    float* __restrict__ out,                  // [32][512][1024] f32
    int* __restrict__ flags)                  // [64] ints, packed (zeroed)
{
    __shared__ float part[8][4][16][20];      // stride 20: <=2-way banks

    const int tid  = threadIdx.x;
    const int lane = tid & 63;
    const int w    = tid >> 6;     // wave 0..7
    const int bh   = w >> 2;       // batch half
    const int kq   = w & 3;        // K quarter
    const int j0   = blockIdx.x * 16;
    const int nl   = lane & 15;
    const int kl   = (lane >> 4) * 8;

    // ---- W_hh -> named registers (once), pinned with asm keep-alive
    const unsigned short* wb0 = Whh + (long)(0 * 1024 + j0 + nl) * 1024 + kq * 256 + kl;
    const unsigned short* wb1 = Whh + (long)(1 * 1024 + j0 + nl) * 1024 + kq * 256 + kl;
    const unsigned short* wb2 = Whh + (long)(2 * 1024 + j0 + nl) * 1024 + kq * 256 + kl;
    const unsigned short* wb3 = Whh + (long)(3 * 1024 + j0 + nl) * 1024 + kq * 256 + kl;
#define DECL_W(g) \
    bf16x8 w##g##0 = *(const bf16x8*)(wb##g +   0); \
    bf16x8 w##g##1 = *(const bf16x8*)(wb##g +  32); \
    bf16x8 w##g##2 = *(const bf16x8*)(wb##g +  64); \
    bf16x8 w##g##3 = *(const bf16x8*)(wb##g +  96); \
    bf16x8 w##g##4 = *(const bf16x8*)(wb##g + 128); \
    bf16x8 w##g##5 = *(const bf16x8*)(wb##g + 160); \
    bf16x8 w##g##6 = *(const bf16x8*)(wb##g + 192); \
    bf16x8 w##g##7 = *(const bf16x8*)(wb##g + 224);
    DECL_W(0) DECL_W(1) DECL_W(2) DECL_W(3)
#define KEEP_W(g) asm volatile("" : "+v"(w##g##0), "+v"(w##g##1), "+v"(w##g##2), \
    "+v"(w##g##3), "+v"(w##g##4), "+v"(w##g##5), "+v"(w##g##6), "+v"(w##g##7));
    KEEP_W(0) KEEP_W(1) KEEP_W(2) KEEP_W(3)

    // A-frag base as 8-byte words: row=bh*16+nl, k base=kq*256+(lane>>4)*8
    const long aq = ((long)(bh * 16 + nl) * 256) + kq * 64 + (lane >> 4) * 2;
    const unsigned long long* hq0p = (const unsigned long long*)h0 + aq;
    const unsigned long long* hq1p = (const unsigned long long*)h1 + aq;

    // epilogue identity: 256 threads, each owns (eb, 2 cols ju, ju+1)
    const bool active = tid < 256;
    const int eb  = tid >> 3;         // batch 0..31 (for tid<256)
    const int pu  = tid & 7;          // uint-column 0..7
    const int ju  = pu * 2;
    const int ebh = eb >> 4, eb16 = eb & 15;
    float creg0 = 0.f, creg1 = 0.f;

    const unsigned* XP32 = (const unsigned*)XP;
    unsigned xpr[4] = {};
    if (active) {
        const long xb = (long)eb * 2048 + (j0 >> 1) + pu;
        xpr[0] = XP32[xb];       xpr[1] = XP32[xb + 512];
        xpr[2] = XP32[xb + 1024]; xpr[3] = XP32[xb + 1536];
    }

    union HU { unsigned long long q[2]; bf16x8 v; };

    for (int t = 0; t < TT; ++t) {
        // ---- full-flag poll (all waves; lanes cover all 64 flags)
        if (t > 0) {
            while (__hip_atomic_load(&flags[lane], __ATOMIC_RELAXED,
                                     __HIP_MEMORY_SCOPE_AGENT) < t)
                __builtin_amdgcn_s_sleep(4);
        }

        // ---- h frags via agent-coherent loads (sc1, no fence needed)
        const unsigned long long* hq = (t & 1) ? hq1p : hq0p;
#define LDH(k) bf16x8 a##k; { \
        unsigned long long lo_ = __hip_atomic_load(hq + (k)*8,     __ATOMIC_RELAXED, __HIP_MEMORY_SCOPE_AGENT); \
        unsigned long long hi_ = __hip_atomic_load(hq + (k)*8 + 1, __ATOMIC_RELAXED, __HIP_MEMORY_SCOPE_AGENT); \
        HU u_; u_.q[0] = lo_; u_.q[1] = hi_; a##k = u_.v; }
        LDH(0) LDH(1) LDH(2) LDH(3) LDH(4) LDH(5) LDH(6) LDH(7)
#undef LDH

        f32x4 acc0 = {}, acc1 = {}, acc2 = {}, acc3 = {};
#define MF(k) \
        acc0 = __builtin_amdgcn_mfma_f32_16x16x32_bf16(a##k, w0##k, acc0, 0, 0, 0); \
        acc1 = __builtin_amdgcn_mfma_f32_16x16x32_bf16(a##k, w1##k, acc1, 0, 0, 0); \
        acc2 = __builtin_amdgcn_mfma_f32_16x16x32_bf16(a##k, w2##k, acc2, 0, 0, 0); \
        acc3 = __builtin_amdgcn_mfma_f32_16x16x32_bf16(a##k, w3##k, acc3, 0, 0, 0);
        MF(0) MF(1) MF(2) MF(3) MF(4) MF(5) MF(6) MF(7)
#undef MF

        // ---- prefetch next step's XP (normal cached loads, used next iter)
        unsigned xpn[4] = {};
        if (active) {
            const long tn = (t + 1 < TT) ? (t + 1) : t;
            const long xb = (tn * 32 + eb) * 2048 + (j0 >> 1) + pu;
            xpn[0] = XP32[xb];        xpn[1] = XP32[xb + 512];
            xpn[2] = XP32[xb + 1024]; xpn[3] = XP32[xb + 1536];
        }

        // ---- write K-partials (stride 20: write quarters 2-way max)
        {
            const int rg = lane >> 4, jl = lane & 15;
#pragma unroll
            for (int r = 0; r < 4; ++r) {
                part[w][0][rg * 4 + r][jl] = acc0[r];
                part[w][1][rg * 4 + r][jl] = acc1[r];
                part[w][2][rg * 4 + r][jl] = acc2[r];
                part[w][3][rg * 4 + r][jl] = acc3[r];
            }
        }
        __syncthreads();

        // ---- epilogue (256 threads x 2 cols): reduce, gates, c/h update
        float hn0 = 0.f, hn1 = 0.f;
        if (active) {
            float gv0[4], gv1[4];
#pragma unroll
            for (int g = 0; g < 4; ++g) {
                float s0 = 0.f, s1 = 0.f;
#pragma unroll
                for (int q = 0; q < 4; ++q) {
                    const float2 p = *(const float2*)&part[ebh * 4 + q][g][eb16][ju];
                    s0 += p.x; s1 += p.y;
                }
                gv0[g] = s0 + bf2f((unsigned short)(xpr[g] & 0xffff));
                gv1[g] = s1 + bf2f((unsigned short)(xpr[g] >> 16));
            }
            float i0 = 1.f / (1.f + __expf(-gv0[0]));
            float f0 = 1.f / (1.f + __expf(-gv0[1]));
            float g0 = tanhf(gv0[2]);
            float o0 = 1.f / (1.f + __expf(-gv0[3]));
            creg0 = f0 * creg0 + i0 * g0;
            hn0 = o0 * tanhf(creg0);
            float i1 = 1.f / (1.f + __expf(-gv1[0]));
            float f1 = 1.f / (1.f + __expf(-gv1[1]));
            float g1 = tanhf(gv1[2]);
            float o1 = 1.f / (1.f + __expf(-gv1[3]));
            creg1 = f1 * creg1 + i1 * g1;
            hn1 = o1 * tanhf(creg1);

            unsigned hv = (unsigned)f2bf(hn0) | ((unsigned)f2bf(hn1) << 16);
            unsigned* ho = (unsigned*)((t & 1) ? h0 : h1);
            __hip_atomic_store(&ho[eb * 512 + (j0 >> 1) + pu], hv,
                               __ATOMIC_RELAXED, __HIP_MEMORY_SCOPE_AGENT);
        }
        __syncthreads();   // drains all waves' h stores (vmcnt(0) at barrier)

        // ---- publish: own flag only (monotonic t+1), no fence
        if (tid == 0)
            __hip_atomic_store(&flags[blockIdx.x], t + 1,
                               __ATOMIC_RELAXED, __HIP_MEMORY_SCOPE_AGENT);

        // ---- out store after flag (off the inter-block critical path)
        if (active) {
            float2 ov; ov.x = hn0; ov.y = hn1;
            *(float2*)&out[((long)eb * TT + t) * HID + j0 + ju] = ov;
#pragma unroll
            for (int g = 0; g < 4; ++g) xpr[g] = xpn[g];
        }
    }
}

extern "C" void kernel_launch(void* const* d_in, const int* in_sizes, int n_in,
                              void* d_out, int out_size, void* d_ws, size_t ws_size,
                              hipStream_t stream)
{
    const float* x   = (const float*)d_in[0];
    const float* Wih = (const float*)d_in[1];
    const float* Whh = (const float*)d_in[2];
    const float* bih = (const float*)d_in[3];
    const float* bhh = (const float*)d_in[4];
    float* out = (float*)d_out;

    char* ws = (char*)d_ws;
    size_t off = 0;
    auto alloc = [&](size_t bytes) {
        char* p = ws + off;
        off = (off + bytes + 255) & ~(size_t)255;
        return p;
    };
    unsigned short* x_bf   = (unsigned short*)alloc((size_t)BB * TT * VOC * 2);
    unsigned short* wih_bf = (unsigned short*)alloc((size_t)G4 * VOC * 2);
    unsigned short* whh_bf = (unsigned short*)alloc((size_t)G4 * HID * 2);
    unsigned short* xp     = (unsigned short*)alloc((size_t)TT * BB * G4 * 2);
    unsigned short* hbuf0  = (unsigned short*)alloc((size_t)BB * HID * 2);
    unsigned short* hbuf1  = (unsigned short*)alloc((size_t)BB * HID * 2);
    int* flags             = (int*)alloc(256);

    // conversions to bf16
    int n4x = BB * TT * VOC / 4;
    cvt_f32_bf16<<<(n4x + 255) / 256, 256, 0, stream>>>(x, x_bf, n4x);
    int n4w = G4 * VOC / 4;
    cvt_f32_bf16<<<(n4w + 255) / 256, 256, 0, stream>>>(Wih, wih_bf, n4w);
    cvt_f32_bf16<<<(n4w + 255) / 256, 256, 0, stream>>>(Whh, whh_bf, n4w);

    // x_proj big GEMM (adds both biases, relayouts to [T][B][4H])
    gemm_xproj<<<4096, 256, 0, stream>>>(x_bf, wih_bf, bih, bhh, xp);

    // init recurrent state + flags (ws is re-poisoned before every launch)
    hipMemsetAsync(hbuf0, 0, (size_t)BB * HID * 2, stream);
    hipMemsetAsync(flags, 0, 256, stream);

    // persistent scan: one launch, 512 internal steps, fence-free flag sync
    lstm_scan<<<NBLK, 512, 0, stream>>>(whh_bf, xp, hbuf0, hbuf1, out, flags);
}

// Round 5
// 2848.628 us; speedup vs baseline: 1.3503x; 1.3503x over previous
//
#include <hip/hip_runtime.h>
#include <hip/hip_bf16.h>
#include <stdint.h>

#define HID 1024
#define VOC 1024
#define BB  32
#define TT  512
#define G4  4096   // 4*HID
#define NBLK 128   // 64 col-slices x 2 batch-halves
#define POIS 0x7FC07FC0u   // 2x bf16 NaN: never produced by o*tanh(c)

typedef float f32x4 __attribute__((ext_vector_type(4)));
typedef short bf16x8 __attribute__((ext_vector_type(8)));
typedef unsigned int u32x4 __attribute__((ext_vector_type(4)));

static __device__ __forceinline__ unsigned short f2bf(float f) {
    union { float f; unsigned u; } v; v.f = f;
    unsigned r = (v.u + 0x7FFFu + ((v.u >> 16) & 1u)) >> 16;  // RTNE
    return (unsigned short)r;
}
static __device__ __forceinline__ float bf2f(unsigned short s) {
    union { unsigned u; float f; } v; v.u = ((unsigned)s) << 16;
    return v.f;
}

// ---------------- f32 -> bf16 conversion, 4 elems/thread ----------------
__global__ void cvt_f32_bf16(const float* __restrict__ in,
                             unsigned short* __restrict__ out, int n4) {
    int i = blockIdx.x * blockDim.x + threadIdx.x;
    if (i >= n4) return;
    float4 v = ((const float4*)in)[i];
    ushort4 o;
    o.x = f2bf(v.x); o.y = f2bf(v.y); o.z = f2bf(v.z); o.w = f2bf(v.w);
    ((ushort4*)out)[i] = o;
}

// ---------------- h-buffer init: buf0 = h(0) = 0, buf1/buf2 = poison ----
__global__ void init_h(unsigned* __restrict__ h0, unsigned* __restrict__ h1,
                       unsigned* __restrict__ h2) {
    int i = blockIdx.x * 256 + threadIdx.x;   // 16384 dwords per buffer
    if (i < BB * HID / 2) { h0[i] = 0u; h1[i] = POIS; h2[i] = POIS; }
}

// ---------------- Phase 1: x_proj GEMM ----------------
// XP[t][b][n] = sum_k x[b][t][k]*W_ih[n][k] + b_ih[n] + b_hh[n], bf16,
// relaid out to [T][B][4H] so the scan reads contiguous per-step chunks.
__global__ __launch_bounds__(256) void gemm_xproj(
    const unsigned short* __restrict__ A, const unsigned short* __restrict__ W,
    const float* __restrict__ bih, const float* __restrict__ bhh,
    unsigned short* __restrict__ XP)
{
    __shared__ unsigned short As[128 * 64];
    __shared__ unsigned short Bs[128 * 64];
    const int tid  = threadIdx.x;
    const int lane = tid & 63;
    const int wid  = tid >> 6;
    const int mt = blockIdx.x & 127;   // 128 M-tiles
    const int nt = blockIdx.x >> 7;    // 32  N-tiles
    const long m0 = (long)mt * 128;
    const long n0 = (long)nt * 128;

    const int wr = wid >> 1, wc = wid & 1;
    const int rl = lane & 15;
    const int kl = (lane >> 4) * 8;

    f32x4 acc[4][4] = {};

    for (int kt = 0; kt < 16; ++kt) {
#pragma unroll
        for (int it = 0; it < 4; ++it) {
            int slot = it * 256 + tid;
            int r = slot >> 3, c8 = slot & 7;
            const unsigned short* ga = A + (m0 + r) * 1024 + kt * 64 + c8 * 8;
            const unsigned short* gb = W + (n0 + r) * 1024 + kt * 64 + c8 * 8;
            char* la = (char*)As + (it * 256 + wid * 64) * 16;
            char* lb = (char*)Bs + (it * 256 + wid * 64) * 16;
            __builtin_amdgcn_global_load_lds(
                (const __attribute__((address_space(1))) void*)ga,
                (__attribute__((address_space(3))) void*)la, 16, 0, 0);
            __builtin_amdgcn_global_load_lds(
                (const __attribute__((address_space(1))) void*)gb,
                (__attribute__((address_space(3))) void*)lb, 16, 0, 0);
        }
        __syncthreads();
#pragma unroll
        for (int kk = 0; kk < 2; ++kk) {
            bf16x8 af[4], bfr[4];
#pragma unroll
            for (int i = 0; i < 4; ++i) {
                int ar = wr * 64 + i * 16 + rl;
                int br = wc * 64 + i * 16 + rl;
                af[i]  = *(const bf16x8*)(As + ar * 64 + kk * 32 + kl);
                bfr[i] = *(const bf16x8*)(Bs + br * 64 + kk * 32 + kl);
            }
#pragma unroll
            for (int i = 0; i < 4; ++i)
#pragma unroll
                for (int j = 0; j < 4; ++j)
                    acc[i][j] = __builtin_amdgcn_mfma_f32_16x16x32_bf16(
                        af[i], bfr[j], acc[i][j], 0, 0, 0);
        }
        __syncthreads();
    }
    // epilogue: m-row = b*512+t  ->  XP row = t*32+b  (relayout)
#pragma unroll
    for (int i = 0; i < 4; ++i)
#pragma unroll
        for (int j = 0; j < 4; ++j)
#pragma unroll
            for (int r = 0; r < 4; ++r) {
                long row = m0 + wr * 64 + i * 16 + (lane >> 4) * 4 + r;
                long col = n0 + wc * 64 + j * 16 + (lane & 15);
                long orow = (row & 511) * 32 + (row >> 9);
                float v = acc[i][j][r] + bih[col] + bhh[col];
                XP[orow * 4096 + col] = f2bf(v);
            }
}

// ---------------- Phase 2: persistent scan, flag-in-data sync ----------------
// 128 blocks x 512 threads. Block = (jblk, bh): 16 hidden cols x 16 batches.
// Wave kq owns K-slice of 128 for all 4 gates (W = 64 VGPRs/lane).
// Sync: NO flags. 3 rotating h buffers; target buffers pre-poisoned with
// bf16-NaN dwords (0x7FC07FC0 -- h=o*tanh(c) can never produce it). Readers
// poll the DATA with coherent (sc0 sc1) loads: non-poison == arrived.
// Safety: block at step t re-poisons its own slice of buf[(t+2)%3] BEFORE
// barrier1; barrier1's vmcnt(0) drain orders poison-ack before this step's
// h-publish, so any block that can observe h(t+1) complete (prerequisite for
// polling buf[(t+2)%3] as h(t+2)) observes the poison too. h(t-1) readers
// are done: seeing h(t) complete implies every block passed its step-t-1
// barrier, which follows all h(t-1) reads.
__global__ __launch_bounds__(512, 2) void lstm_scan(
    const unsigned short* __restrict__ Whh,   // [4096][1024] bf16
    const unsigned short* __restrict__ XP,    // [512][32][4096] bf16
    unsigned* __restrict__ hb0,               // [32*512] dwords: h(0)=0
    unsigned* __restrict__ hb1,               // poisoned
    unsigned* __restrict__ hb2,               // poisoned
    float* __restrict__ out)                  // [32][512][1024] f32
{
    __shared__ float part[8][4][16][20];      // 40KB; <=2-way banked

    const int tid  = threadIdx.x;
    const int lane = tid & 63;
    const int kq   = tid >> 6;       // wave = K-slice of 128
    const int nl   = lane & 15;      // col-in-16 (W) / batch-in-16 (A row)
    const int kh   = lane >> 4;      // k sub-offset *8
    const int jblk = blockIdx.x & 63;
    const int bh   = blockIdx.x >> 6;      // batch half
    const int j0   = jblk * 16;

    // ---- W_hh frags: gate g, kt 0..3; 64 VGPRs total
#define DECL_W(g) \
    const unsigned short* wb##g = Whh + (long)(g * 1024 + j0 + nl) * 1024 + kq * 128 + kh * 8; \
    bf16x8 w##g##0 = *(const bf16x8*)(wb##g +  0); \
    bf16x8 w##g##1 = *(const bf16x8*)(wb##g + 32); \
    bf16x8 w##g##2 = *(const bf16x8*)(wb##g + 64); \
    bf16x8 w##g##3 = *(const bf16x8*)(wb##g + 96);
    DECL_W(0) DECL_W(1) DECL_W(2) DECL_W(3)

    // ---- poll/A-frag byte offset (frag kt at +kt*64 bytes)
    const long pOff = ((long)(bh * 16 + nl) * 1024 + kq * 128 + kh * 8) * 2;

    // ---- epilogue identity: tid<128 owns (batch eb, packed col pu)
    const bool act  = tid < 128;
    const int eb16  = tid >> 3;      // batch within half (0..15)
    const int pu    = tid & 7;       // packed dword col
    const int ju    = pu * 2;
    const int eb    = bh * 16 + eb16;
    const int hword = eb * 512 + jblk * 8 + pu;   // dword index in h buffers
    float creg0 = 0.f, creg1 = 0.f;

    const unsigned* XP32 = (const unsigned*)XP;
    unsigned xpr[4] = {};
    if (act) {
        const long xb = (long)eb * 2048 + jblk * 8 + pu;
        xpr[0] = XP32[xb];        xpr[1] = XP32[xb + 512];
        xpr[2] = XP32[xb + 1024]; xpr[3] = XP32[xb + 1536];
    }

    // rotating buffers: read h(t), write h(t+1), poison for h(t+2)
    unsigned* rbuf = hb0; unsigned* wbuf = hb1; unsigned* pbuf = hb2;
    const unsigned pois = POIS;

    union CV { u32x4 u; bf16x8 v; };

    for (int t = 0; t < TT; ++t) {
        // ---- poll h(t): coherent loads, non-poison == data arrived
        u32x4 f0, f1, f2, f3;
        {
            const char* rb = (const char*)rbuf + pOff;
            while (true) {
                asm volatile("global_load_dwordx4 %0, %1, off sc0 sc1"
                             : "=v"(f0) : "v"(rb) : "memory");
                asm volatile("global_load_dwordx4 %0, %1, off offset:64 sc0 sc1"
                             : "=v"(f1) : "v"(rb) : "memory");
                asm volatile("global_load_dwordx4 %0, %1, off offset:128 sc0 sc1"
                             : "=v"(f2) : "v"(rb) : "memory");
                asm volatile("global_load_dwordx4 %0, %1, off offset:192 sc0 sc1"
                             : "=v"(f3) : "v"(rb) : "memory");
                asm volatile("s_waitcnt vmcnt(0)" ::: "memory");
                int dirty = 0;
#pragma unroll
                for (int i = 0; i < 4; ++i)
                    dirty |= (f0[i] == POIS) | (f1[i] == POIS) |
                             (f2[i] == POIS) | (f3[i] == POIS);
                if (!__any(dirty)) break;
                __builtin_amdgcn_s_sleep(1);
            }
        }

        // ---- poison own slice of buf[(t+2)%3] (ordered before h-publish
        //      by barrier1's vmcnt drain); prefetch next XP
        unsigned xpn[4] = {};
        if (act) {
            unsigned* pp = pbuf + hword;
            asm volatile("global_store_dword %0, %1, off sc0 sc1"
                         :: "v"(pp), "v"(pois) : "memory");
            const long tn = (t + 1 < TT) ? (t + 1) : t;
            const long xb = (tn * 32 + eb) * 2048 + jblk * 8 + pu;
            xpn[0] = XP32[xb];        xpn[1] = XP32[xb + 512];
            xpn[2] = XP32[xb + 1024]; xpn[3] = XP32[xb + 1536];
        }

        // ---- keep W resident; 16 MFMAs (4 gates x 4 kt)
        asm volatile("" : "+v"(w00), "+v"(w01), "+v"(w02), "+v"(w03),
                          "+v"(w10), "+v"(w11), "+v"(w12), "+v"(w13),
                          "+v"(w20), "+v"(w21), "+v"(w22), "+v"(w23),
                          "+v"(w30), "+v"(w31), "+v"(w32), "+v"(w33));
        f32x4 acc0 = {}, acc1 = {}, acc2 = {}, acc3 = {};
        {
            CV c0, c1, c2, c3;
            c0.u = f0; c1.u = f1; c2.u = f2; c3.u = f3;
            acc0 = __builtin_amdgcn_mfma_f32_16x16x32_bf16(c0.v, w00, acc0, 0, 0, 0);
            acc1 = __builtin_amdgcn_mfma_f32_16x16x32_bf16(c0.v, w10, acc1, 0, 0, 0);
            acc2 = __builtin_amdgcn_mfma_f32_16x16x32_bf16(c0.v, w20, acc2, 0, 0, 0);
            acc3 = __builtin_amdgcn_mfma_f32_16x16x32_bf16(c0.v, w30, acc3, 0, 0, 0);
            acc0 = __builtin_amdgcn_mfma_f32_16x16x32_bf16(c1.v, w01, acc0, 0, 0, 0);
            acc1 = __builtin_amdgcn_mfma_f32_16x16x32_bf16(c1.v, w11, acc1, 0, 0, 0);
            acc2 = __builtin_amdgcn_mfma_f32_16x16x32_bf16(c1.v, w21, acc2, 0, 0, 0);
            acc3 = __builtin_amdgcn_mfma_f32_16x16x32_bf16(c1.v, w31, acc3, 0, 0, 0);
            acc0 = __builtin_amdgcn_mfma_f32_16x16x32_bf16(c2.v, w02, acc0, 0, 0, 0);
            acc1 = __builtin_amdgcn_mfma_f32_16x16x32_bf16(c2.v, w12, acc1, 0, 0, 0);
            acc2 = __builtin_amdgcn_mfma_f32_16x16x32_bf16(c2.v, w22, acc2, 0, 0, 0);
            acc3 = __builtin_amdgcn_mfma_f32_16x16x32_bf16(c2.v, w32, acc3, 0, 0, 0);
            acc0 = __builtin_amdgcn_mfma_f32_16x16x32_bf16(c3.v, w03, acc0, 0, 0, 0);
            acc1 = __builtin_amdgcn_mfma_f32_16x16x32_bf16(c3.v, w13, acc1, 0, 0, 0);
            acc2 = __builtin_amdgcn_mfma_f32_16x16x32_bf16(c3.v, w23, acc2, 0, 0, 0);
            acc3 = __builtin_amdgcn_mfma_f32_16x16x32_bf16(c3.v, w33, acc3, 0, 0, 0);
        }

        // ---- K-partials to LDS (<=2-way banked)
#pragma unroll
        for (int r = 0; r < 4; ++r) {
            part[kq][0][kh * 4 + r][nl] = acc0[r];
            part[kq][1][kh * 4 + r][nl] = acc1[r];
            part[kq][2][kh * 4 + r][nl] = acc2[r];
            part[kq][3][kh * 4 + r][nl] = acc3[r];
        }
        __syncthreads();   // barrier1: part complete; poison+stores drained

        // ---- reduce 8 K-slices (reads only; frees LDS at barrier2)
        float gv0[4], gv1[4];
        if (act) {
#pragma unroll
            for (int g = 0; g < 4; ++g) {
                float a0 = 0.f, a1 = 0.f;
#pragma unroll
                for (int q = 0; q < 8; ++q) {
                    const float2 p = *(const float2*)&part[q][g][eb16][ju];
                    a0 += p.x; a1 += p.y;
                }
                gv0[g] = a0 + bf2f((unsigned short)(xpr[g] & 0xffff));
                gv1[g] = a1 + bf2f((unsigned short)(xpr[g] >> 16));
            }
        }
        __syncthreads();   // barrier2: part reads done; waves free to advance

        // ---- gates, state update, publish h(t+1) (off other waves' path)
        if (act) {
            float i0 = 1.f / (1.f + __expf(-gv0[0]));
            float f0g = 1.f / (1.f + __expf(-gv0[1]));
            float g0 = tanhf(gv0[2]);
            float o0 = 1.f / (1.f + __expf(-gv0[3]));
            creg0 = f0g * creg0 + i0 * g0;
            float hn0 = o0 * tanhf(creg0);
            float i1 = 1.f / (1.f + __expf(-gv1[0]));
            float f1g = 1.f / (1.f + __expf(-gv1[1]));
            float g1 = tanhf(gv1[2]);
            float o1 = 1.f / (1.f + __expf(-gv1[3]));
            creg1 = f1g * creg1 + i1 * g1;
            float hn1 = o1 * tanhf(creg1);

            unsigned hv = (unsigned)f2bf(hn0) | ((unsigned)f2bf(hn1) << 16);
            unsigned* wp = wbuf + hword;
            asm volatile("global_store_dword %0, %1, off sc0 sc1"
                         :: "v"(wp), "v"(hv) : "memory");

            float2 ov; ov.x = hn0; ov.y = hn1;
            *(float2*)&out[((long)eb * TT + t) * HID + j0 + ju] = ov;
#pragma unroll
            for (int g = 0; g < 4; ++g) xpr[g] = xpn[g];
        }

        // rotate: read <- write <- poison <- read
        unsigned* tmp = rbuf; rbuf = wbuf; wbuf = pbuf; pbuf = tmp;
    }
}

extern "C" void kernel_launch(void* const* d_in, const int* in_sizes, int n_in,
                              void* d_out, int out_size, void* d_ws, size_t ws_size,
                              hipStream_t stream)
{
    const float* x   = (const float*)d_in[0];
    const float* Wih = (const float*)d_in[1];
    const float* Whh = (const float*)d_in[2];
    const float* bih = (const float*)d_in[3];
    const float* bhh = (const float*)d_in[4];
    float* out = (float*)d_out;

    char* ws = (char*)d_ws;
    size_t off = 0;
    auto alloc = [&](size_t bytes) {
        char* p = ws + off;
        off = (off + bytes + 255) & ~(size_t)255;
        return p;
    };
    unsigned short* x_bf   = (unsigned short*)alloc((size_t)BB * TT * VOC * 2);
    unsigned short* wih_bf = (unsigned short*)alloc((size_t)G4 * VOC * 2);
    unsigned short* whh_bf = (unsigned short*)alloc((size_t)G4 * HID * 2);
    unsigned short* xp     = (unsigned short*)alloc((size_t)TT * BB * G4 * 2);
    unsigned* hb0          = (unsigned*)alloc((size_t)BB * HID * 2);
    unsigned* hb1          = (unsigned*)alloc((size_t)BB * HID * 2);
    unsigned* hb2          = (unsigned*)alloc((size_t)BB * HID * 2);

    // conversions to bf16
    int n4x = BB * TT * VOC / 4;
    cvt_f32_bf16<<<(n4x + 255) / 256, 256, 0, stream>>>(x, x_bf, n4x);
    int n4w = G4 * VOC / 4;
    cvt_f32_bf16<<<(n4w + 255) / 256, 256, 0, stream>>>(Wih, wih_bf, n4w);
    cvt_f32_bf16<<<(n4w + 255) / 256, 256, 0, stream>>>(Whh, whh_bf, n4w);

    // x_proj big GEMM (adds both biases, relayouts to [T][B][4H])
    gemm_xproj<<<4096, 256, 0, stream>>>(x_bf, wih_bf, bih, bhh, xp);

    // h buffers: buf0 = zeros (h(0)), buf1/buf2 = NaN poison
    init_h<<<64, 256, 0, stream>>>(hb0, hb1, hb2);

    // persistent scan: one launch, 512 steps, data-is-the-flag sync
    lstm_scan<<<NBLK, 512, 0, stream>>>(whh_bf, xp, hb0, hb1, hb2, out);
}

// Round 6
// 2715.316 us; speedup vs baseline: 1.4166x; 1.0491x over previous
//
#include <hip/hip_runtime.h>
#include <hip/hip_bf16.h>
#include <stdint.h>

#define HID 1024
#define VOC 1024
#define BB  32
#define TT  512
#define G4  4096   // 4*HID
#define NBLK 128   // 64 col-slices x 2 batch-halves
#define POIS 0x7FC07FC0u   // 2x bf16 NaN: never produced by o*tanh(c) (|h|<1)

typedef float f32x4 __attribute__((ext_vector_type(4)));
typedef short bf16x8 __attribute__((ext_vector_type(8)));
typedef unsigned int u32x4 __attribute__((ext_vector_type(4)));

static __device__ __forceinline__ unsigned short f2bf(float f) {
    union { float f; unsigned u; } v; v.f = f;
    unsigned r = (v.u + 0x7FFFu + ((v.u >> 16) & 1u)) >> 16;  // RTNE
    return (unsigned short)r;
}
static __device__ __forceinline__ float bf2f(unsigned short s) {
    union { unsigned u; float f; } v; v.u = ((unsigned)s) << 16;
    return v.f;
}
static __device__ __forceinline__ int vd(u32x4 v) {   // any dword poisoned
    return (v[0] == POIS) | (v[1] == POIS) | (v[2] == POIS) | (v[3] == POIS);
}

// ---------------- f32 -> bf16 conversion, 4 elems/thread ----------------
__global__ void cvt_f32_bf16(const float* __restrict__ in,
                             unsigned short* __restrict__ out, int n4) {
    int i = blockIdx.x * blockDim.x + threadIdx.x;
    if (i >= n4) return;
    float4 v = ((const float4*)in)[i];
    ushort4 o;
    o.x = f2bf(v.x); o.y = f2bf(v.y); o.z = f2bf(v.z); o.w = f2bf(v.w);
    ((ushort4*)out)[i] = o;
}

// ---------------- h-buffer init: buf0 = h(0) = 0, buf1/buf2 = poison ----
__global__ void init_h(unsigned* __restrict__ h0, unsigned* __restrict__ h1,
                       unsigned* __restrict__ h2) {
    int i = blockIdx.x * 256 + threadIdx.x;   // 16384 dwords per buffer
    if (i < BB * HID / 2) { h0[i] = 0u; h1[i] = POIS; h2[i] = POIS; }
}

// ---------------- Phase 1: x_proj GEMM ----------------
// XP[t][b][n] = sum_k x[b][t][k]*W_ih[n][k] + b_ih[n] + b_hh[n], bf16,
// relaid out to [T][B][4H] so the scan reads contiguous per-step chunks.
__global__ __launch_bounds__(256) void gemm_xproj(
    const unsigned short* __restrict__ A, const unsigned short* __restrict__ W,
    const float* __restrict__ bih, const float* __restrict__ bhh,
    unsigned short* __restrict__ XP)
{
    __shared__ unsigned short As[128 * 64];
    __shared__ unsigned short Bs[128 * 64];
    const int tid  = threadIdx.x;
    const int lane = tid & 63;
    const int wid  = tid >> 6;
    const int mt = blockIdx.x & 127;   // 128 M-tiles
    const int nt = blockIdx.x >> 7;    // 32  N-tiles
    const long m0 = (long)mt * 128;
    const long n0 = (long)nt * 128;

    const int wr = wid >> 1, wc = wid & 1;
    const int rl = lane & 15;
    const int kl = (lane >> 4) * 8;

    f32x4 acc[4][4] = {};

    for (int kt = 0; kt < 16; ++kt) {
#pragma unroll
        for (int it = 0; it < 4; ++it) {
            int slot = it * 256 + tid;
            int r = slot >> 3, c8 = slot & 7;
            const unsigned short* ga = A + (m0 + r) * 1024 + kt * 64 + c8 * 8;
            const unsigned short* gb = W + (n0 + r) * 1024 + kt * 64 + c8 * 8;
            char* la = (char*)As + (it * 256 + wid * 64) * 16;
            char* lb = (char*)Bs + (it * 256 + wid * 64) * 16;
            __builtin_amdgcn_global_load_lds(
                (const __attribute__((address_space(1))) void*)ga,
                (__attribute__((address_space(3))) void*)la, 16, 0, 0);
            __builtin_amdgcn_global_load_lds(
                (const __attribute__((address_space(1))) void*)gb,
                (__attribute__((address_space(3))) void*)lb, 16, 0, 0);
        }
        __syncthreads();
#pragma unroll
        for (int kk = 0; kk < 2; ++kk) {
            bf16x8 af[4], bfr[4];
#pragma unroll
            for (int i = 0; i < 4; ++i) {
                int ar = wr * 64 + i * 16 + rl;
                int br = wc * 64 + i * 16 + rl;
                af[i]  = *(const bf16x8*)(As + ar * 64 + kk * 32 + kl);
                bfr[i] = *(const bf16x8*)(Bs + br * 64 + kk * 32 + kl);
            }
#pragma unroll
            for (int i = 0; i < 4; ++i)
#pragma unroll
                for (int j = 0; j < 4; ++j)
                    acc[i][j] = __builtin_amdgcn_mfma_f32_16x16x32_bf16(
                        af[i], bfr[j], acc[i][j], 0, 0, 0);
        }
        __syncthreads();
    }
    // epilogue: m-row = b*512+t  ->  XP row = t*32+b  (relayout)
#pragma unroll
    for (int i = 0; i < 4; ++i)
#pragma unroll
        for (int j = 0; j < 4; ++j)
#pragma unroll
            for (int r = 0; r < 4; ++r) {
                long row = m0 + wr * 64 + i * 16 + (lane >> 4) * 4 + r;
                long col = n0 + wc * 64 + j * 16 + (lane & 15);
                long orow = (row & 511) * 32 + (row >> 9);
                float v = acc[i][j][r] + bih[col] + bhh[col];
                XP[orow * 4096 + col] = f2bf(v);
            }
}

// ---------------- Phase 2: persistent scan, flag-in-data sync ----------------
// 128 blocks x 512 threads. Block = (jblk, bh): 16 hidden cols x 16 batches.
// Wave kq owns K-slice of 128 for all 4 gates. W_hh: gates i,f in 32 VGPRs
// (small enough to provably stay resident); gates g,o staged ONCE in LDS
// (XOR-swizzled, conflict-free reads) -- residency guaranteed, no allocator
// roulette. Sync: 3 rotating h buffers, bf16-NaN poison, readers poll the
// DATA itself (sc0 sc1); selective per-vector reload on retry. part[] is
// double-buffered (stride 18: conflict-free + 8B-aligned) -> ONE barrier
// per step. XP prefetch issued AFTER the barrier so its latency never sits
// on the barrier's vmcnt(0) drain.
__global__ __launch_bounds__(512, 2) void lstm_scan(
    const unsigned short* __restrict__ Whh,   // [4096][1024] bf16
    const unsigned short* __restrict__ XP,    // [512][32][4096] bf16
    unsigned* __restrict__ hb0,               // [32*512] dwords: h(0)=0
    unsigned* __restrict__ hb1,               // poisoned
    unsigned* __restrict__ hb2,               // poisoned
    float* __restrict__ out)                  // [32][512][1024] f32
{
    __shared__ unsigned short Wlds[32 * 1024];     // 64KB: gates g,o swizzled
    __shared__ float part[2][8][4][16][18];        // 72KB: dbuf partials

    const int tid  = threadIdx.x;
    const int lane = tid & 63;
    const int kq   = tid >> 6;       // wave = K-slice of 128
    const int nl   = lane & 15;      // col-in-16 (W) / batch-in-16 (A row)
    const int kh   = lane >> 4;      // k sub-offset *8
    const int jblk = blockIdx.x & 63;
    const int bh   = blockIdx.x >> 6;      // batch half
    const int j0   = jblk * 16;

    // ---- stage W gates 2,3 (g,o) into LDS, swizzled ^((row&7)<<4), once
    for (int i = 0; i < 8; ++i) {
        int g16 = tid + i * 512;          // granule 0..4095
        int rn  = g16 >> 7;               // lds row 0..31
        int kc  = g16 & 127;              // 16B granule in row
        bf16x8 v = *(const bf16x8*)(Whh +
            (long)((2 + (rn >> 4)) * 1024 + j0 + (rn & 15)) * 1024 + kc * 8);
        *(bf16x8*)((char*)Wlds + ((rn * 2048 + kc * 16) ^ ((rn & 7) << 4))) = v;
    }

    // ---- W gates 0,1 (i,f) -> 32 VGPRs
    const unsigned short* wbi = Whh + (long)(j0 + nl) * 1024 + kq * 128 + kh * 8;
    const unsigned short* wbf = Whh + (long)(1024 + j0 + nl) * 1024 + kq * 128 + kh * 8;
    bf16x8 wi0 = *(const bf16x8*)(wbi +  0), wi1 = *(const bf16x8*)(wbi + 32),
           wi2 = *(const bf16x8*)(wbi + 64), wi3 = *(const bf16x8*)(wbi + 96);
    bf16x8 wf0 = *(const bf16x8*)(wbf +  0), wf1 = *(const bf16x8*)(wbf + 32),
           wf2 = *(const bf16x8*)(wbf + 64), wf3 = *(const bf16x8*)(wbf + 96);

    // ---- poll/A-frag byte offset (frag kt at +kt*64 bytes)
    const long pOff = ((long)(bh * 16 + nl) * 1024 + kq * 128 + kh * 8) * 2;
    const int  swzx = (nl & 7) << 4;
    const int  kb   = (kq * 128 + kh * 8) * 2;   // byte col base in Wlds row

    // ---- epilogue identity: tid<128 owns (batch eb, packed col pu)
    const bool act  = tid < 128;
    const int eb16  = tid >> 3;      // batch within half (0..15)
    const int pu    = tid & 7;       // packed dword col
    const int ju    = pu * 2;
    const int eb    = bh * 16 + eb16;
    const int hword = eb * 512 + jblk * 8 + pu;   // dword index in h buffers
    float creg0 = 0.f, creg1 = 0.f;

    const unsigned* XP32 = (const unsigned*)XP;
    unsigned xpr[4] = {};
    if (act) {
        const long xb = (long)eb * 2048 + jblk * 8 + pu;
        xpr[0] = XP32[xb];        xpr[1] = XP32[xb + 512];
        xpr[2] = XP32[xb + 1024]; xpr[3] = XP32[xb + 1536];
    }

    // rotating buffers: read h(t), write h(t+1), poison for h(t+2)
    unsigned* rbuf = hb0; unsigned* wbuf = hb1; unsigned* pbuf = hb2;
    const unsigned pois = POIS;

    union CV { u32x4 u; bf16x8 v; };

    __syncthreads();   // Wlds staged

    for (int t = 0; t < TT; ++t) {
        const int tb = t & 1;

        // ---- poll h(t): coherent loads; retries reload only dirty vectors
        u32x4 f0, f1, f2, f3;
        {
            const char* rb = (const char*)rbuf + pOff;
            asm volatile("global_load_dwordx4 %0, %1, off sc0 sc1"
                         : "=v"(f0) : "v"(rb) : "memory");
            asm volatile("global_load_dwordx4 %0, %1, off offset:64 sc0 sc1"
                         : "=v"(f1) : "v"(rb) : "memory");
            asm volatile("global_load_dwordx4 %0, %1, off offset:128 sc0 sc1"
                         : "=v"(f2) : "v"(rb) : "memory");
            asm volatile("global_load_dwordx4 %0, %1, off offset:192 sc0 sc1"
                         : "=v"(f3) : "v"(rb) : "memory");
            asm volatile("s_waitcnt vmcnt(0)" ::: "memory");
            __builtin_amdgcn_sched_barrier(0);
            int d0 = vd(f0), d1 = vd(f1), d2 = vd(f2), d3 = vd(f3);
            while (__any(d0 | d1 | d2 | d3)) {
                __builtin_amdgcn_s_sleep(2);
                if (d0) asm volatile("global_load_dwordx4 %0, %1, off sc0 sc1"
                                     : "=v"(f0) : "v"(rb) : "memory");
                if (d1) asm volatile("global_load_dwordx4 %0, %1, off offset:64 sc0 sc1"
                                     : "=v"(f1) : "v"(rb) : "memory");
                if (d2) asm volatile("global_load_dwordx4 %0, %1, off offset:128 sc0 sc1"
                                     : "=v"(f2) : "v"(rb) : "memory");
                if (d3) asm volatile("global_load_dwordx4 %0, %1, off offset:192 sc0 sc1"
                                     : "=v"(f3) : "v"(rb) : "memory");
                asm volatile("s_waitcnt vmcnt(0)" ::: "memory");
                __builtin_amdgcn_sched_barrier(0);
                if (d0) d0 = vd(f0);
                if (d1) d1 = vd(f1);
                if (d2) d2 = vd(f2);
                if (d3) d3 = vd(f3);
            }
        }

        // ---- poison own slice of buf[(t+2)%3]; drained by the barrier's
        //      vmcnt(0) => globally ordered before this step's h-publish
        if (act) {
            unsigned* pp = pbuf + hword;
            asm volatile("global_store_dword %0, %1, off sc0 sc1"
                         :: "v"(pp), "v"(pois) : "memory");
        }

        // ---- 16 MFMAs: gates i,f from VGPR W; gates g,o from LDS W
        asm volatile("" : "+v"(wi0), "+v"(wi1), "+v"(wi2), "+v"(wi3),
                          "+v"(wf0), "+v"(wf1), "+v"(wf2), "+v"(wf3));
        f32x4 acc0 = {}, acc1 = {}, acc2 = {}, acc3 = {};
        {
            CV c0, c1, c2, c3;
            c0.u = f0; c1.u = f1; c2.u = f2; c3.u = f3;
            const char* wl = (const char*)Wlds;
            bf16x8 wg0 = *(const bf16x8*)(wl + ((nl * 2048 + kb +   0) ^ swzx));
            bf16x8 wg1 = *(const bf16x8*)(wl + ((nl * 2048 + kb +  64) ^ swzx));
            bf16x8 wg2 = *(const bf16x8*)(wl + ((nl * 2048 + kb + 128) ^ swzx));
            bf16x8 wg3 = *(const bf16x8*)(wl + ((nl * 2048 + kb + 192) ^ swzx));
            bf16x8 wo0 = *(const bf16x8*)(wl + 32768 + ((nl * 2048 + kb +   0) ^ swzx));
            bf16x8 wo1 = *(const bf16x8*)(wl + 32768 + ((nl * 2048 + kb +  64) ^ swzx));
            bf16x8 wo2 = *(const bf16x8*)(wl + 32768 + ((nl * 2048 + kb + 128) ^ swzx));
            bf16x8 wo3 = *(const bf16x8*)(wl + 32768 + ((nl * 2048 + kb + 192) ^ swzx));
            acc0 = __builtin_amdgcn_mfma_f32_16x16x32_bf16(c0.v, wi0, acc0, 0, 0, 0);
            acc1 = __builtin_amdgcn_mfma_f32_16x16x32_bf16(c0.v, wf0, acc1, 0, 0, 0);
            acc0 = __builtin_amdgcn_mfma_f32_16x16x32_bf16(c1.v, wi1, acc0, 0, 0, 0);
            acc1 = __builtin_amdgcn_mfma_f32_16x16x32_bf16(c1.v, wf1, acc1, 0, 0, 0);
            acc0 = __builtin_amdgcn_mfma_f32_16x16x32_bf16(c2.v, wi2, acc0, 0, 0, 0);
            acc1 = __builtin_amdgcn_mfma_f32_16x16x32_bf16(c2.v, wf2, acc1, 0, 0, 0);
            acc0 = __builtin_amdgcn_mfma_f32_16x16x32_bf16(c3.v, wi3, acc0, 0, 0, 0);
            acc1 = __builtin_amdgcn_mfma_f32_16x16x32_bf16(c3.v, wf3, acc1, 0, 0, 0);
            acc2 = __builtin_amdgcn_mfma_f32_16x16x32_bf16(c0.v, wg0, acc2, 0, 0, 0);
            acc3 = __builtin_amdgcn_mfma_f32_16x16x32_bf16(c0.v, wo0, acc3, 0, 0, 0);
            acc2 = __builtin_amdgcn_mfma_f32_16x16x32_bf16(c1.v, wg1, acc2, 0, 0, 0);
            acc3 = __builtin_amdgcn_mfma_f32_16x16x32_bf16(c1.v, wo1, acc3, 0, 0, 0);
            acc2 = __builtin_amdgcn_mfma_f32_16x16x32_bf16(c2.v, wg2, acc2, 0, 0, 0);
            acc3 = __builtin_amdgcn_mfma_f32_16x16x32_bf16(c2.v, wo2, acc3, 0, 0, 0);
            acc2 = __builtin_amdgcn_mfma_f32_16x16x32_bf16(c3.v, wg3, acc2, 0, 0, 0);
            acc3 = __builtin_amdgcn_mfma_f32_16x16x32_bf16(c3.v, wo3, acc3, 0, 0, 0);
        }

        // ---- K-partials to LDS dbuf (stride 18: conflict-free, 8B-aligned)
#pragma unroll
        for (int r = 0; r < 4; ++r) {
            part[tb][kq][0][kh * 4 + r][nl] = acc0[r];
            part[tb][kq][1][kh * 4 + r][nl] = acc1[r];
            part[tb][kq][2][kh * 4 + r][nl] = acc2[r];
            part[tb][kq][3][kh * 4 + r][nl] = acc3[r];
        }
        __syncthreads();   // ONE barrier: part ready; poison store drained

        // ---- reduce 8 K-slices, gates, state update, publish h(t+1)
        if (act) {
            float gv0[4], gv1[4];
#pragma unroll
            for (int g = 0; g < 4; ++g) {
                float a0 = 0.f, a1 = 0.f;
#pragma unroll
                for (int q = 0; q < 8; ++q) {
                    const float2 p = *(const float2*)&part[tb][q][g][eb16][ju];
                    a0 += p.x; a1 += p.y;
                }
                gv0[g] = a0 + bf2f((unsigned short)(xpr[g] & 0xffff));
                gv1[g] = a1 + bf2f((unsigned short)(xpr[g] >> 16));
            }
            float i0 = 1.f / (1.f + __expf(-gv0[0]));
            float f0g = 1.f / (1.f + __expf(-gv0[1]));
            float g0 = tanhf(gv0[2]);
            float o0 = 1.f / (1.f + __expf(-gv0[3]));
            creg0 = f0g * creg0 + i0 * g0;
            float hn0 = o0 * tanhf(creg0);
            float i1 = 1.f / (1.f + __expf(-gv1[0]));
            float f1g = 1.f / (1.f + __expf(-gv1[1]));
            float g1 = tanhf(gv1[2]);
            float o1 = 1.f / (1.f + __expf(-gv1[3]));
            creg1 = f1g * creg1 + i1 * g1;
            float hn1 = o1 * tanhf(creg1);

            unsigned hv = (unsigned)f2bf(hn0) | ((unsigned)f2bf(hn1) << 16);
            unsigned* wp = wbuf + hword;
            asm volatile("global_store_dword %0, %1, off sc0 sc1"
                         :: "v"(wp), "v"(hv) : "memory");

            // out store + next-step XP prefetch: AFTER publish, latency
            // hidden under next step's poll+MFMA (drained at next barrier)
            float2 ov; ov.x = hn0; ov.y = hn1;
            *(float2*)&out[((long)eb * TT + t) * HID + j0 + ju] = ov;
            const long tn = (t + 1 < TT) ? (t + 1) : t;
            const long xb = (tn * 32 + eb) * 2048 + jblk * 8 + pu;
            xpr[0] = XP32[xb];        xpr[1] = XP32[xb + 512];
            xpr[2] = XP32[xb + 1024]; xpr[3] = XP32[xb + 1536];
        }

        // rotate: read <- write <- poison <- read
        unsigned* tmp = rbuf; rbuf = wbuf; wbuf = pbuf; pbuf = tmp;
    }
}

extern "C" void kernel_launch(void* const* d_in, const int* in_sizes, int n_in,
                              void* d_out, int out_size, void* d_ws, size_t ws_size,
                              hipStream_t stream)
{
    const float* x   = (const float*)d_in[0];
    const float* Wih = (const float*)d_in[1];
    const float* Whh = (const float*)d_in[2];
    const float* bih = (const float*)d_in[3];
    const float* bhh = (const float*)d_in[4];
    float* out = (float*)d_out;

    char* ws = (char*)d_ws;
    size_t off = 0;
    auto alloc = [&](size_t bytes) {
        char* p = ws + off;
        off = (off + bytes + 255) & ~(size_t)255;
        return p;
    };
    unsigned short* x_bf   = (unsigned short*)alloc((size_t)BB * TT * VOC * 2);
    unsigned short* wih_bf = (unsigned short*)alloc((size_t)G4 * VOC * 2);
    unsigned short* whh_bf = (unsigned short*)alloc((size_t)G4 * HID * 2);
    unsigned short* xp     = (unsigned short*)alloc((size_t)TT * BB * G4 * 2);
    unsigned* hb0          = (unsigned*)alloc((size_t)BB * HID * 2);
    unsigned* hb1          = (unsigned*)alloc((size_t)BB * HID * 2);
    unsigned* hb2          = (unsigned*)alloc((size_t)BB * HID * 2);

    // conversions to bf16
    int n4x = BB * TT * VOC / 4;
    cvt_f32_bf16<<<(n4x + 255) / 256, 256, 0, stream>>>(x, x_bf, n4x);
    int n4w = G4 * VOC / 4;
    cvt_f32_bf16<<<(n4w + 255) / 256, 256, 0, stream>>>(Wih, wih_bf, n4w);
    cvt_f32_bf16<<<(n4w + 255) / 256, 256, 0, stream>>>(Whh, whh_bf, n4w);

    // x_proj big GEMM (adds both biases, relayouts to [T][B][4H])
    gemm_xproj<<<4096, 256, 0, stream>>>(x_bf, wih_bf, bih, bhh, xp);

    // h buffers: buf0 = zeros (h(0)), buf1/buf2 = NaN poison
    init_h<<<64, 256, 0, stream>>>(hb0, hb1, hb2);

    // persistent scan: one launch, 512 steps, data-is-the-flag sync
    lstm_scan<<<NBLK, 512, 0, stream>>>(whh_bf, xp, hb0, hb1, hb2, out);
}